// Round 20
// baseline (140.132 us; speedup 1.0000x reference)
//
#include <hip/hip_runtime.h>
#include <math.h>

#define N_QUBITS 24
#define N_BLOCKS 4
#define NSTATE (1 << N_QUBITS)

// Qubit q <-> flat-index bit (23 - q).
// Per block (by commutation): RY(0); for q=1..23: RY(q); CNOT(q-1,q)
// Ping-pong buffers, alternating layouts (race-free: src != dst).
//   standard: addr = e23..e0
//   pi2:      addr = blk<<15 | G<<5 | e0..4,  blk = e5..13, G bit k = e(14+k)
// Schedule (6 dispatches):
//   fused   : block0 analytic product state x block1 q0..9 -> d_ws pi2 (W only)
//   P23(1)  : d_ws -> d_out ;  P1(2): d_out -> d_ws ;  P23(2): d_ws -> d_out
//   P1(3)   : d_out -> d_ws ;  P23(3)+SQUARE: d_ws -> d_out
// R20: lane-xor masks 1/2/8 via DPP (R17-proven). Mask 4 via DPP with the
// CORRECT shift convention (R19's bug): row_shr:N -> dst[i]=src[i-N],
// row_shl:N -> dst[i]=src[i+N] (per the canonical GCN prefix-sum idiom).
// Masks 16/32 stay __shfl_xor (ds_swizzle).

// ---- VALU lane-exchange primitives ----
template <int CTRL>
__device__ __forceinline__ float dpp_mov(float v) {
    return __int_as_float(__builtin_amdgcn_update_dpp(
        __float_as_int(v), __float_as_int(v), CTRL, 0xF, 0xF, false));
}
template <int MASK>
__device__ __forceinline__ float xor_lanes(float v, int lane) {
    if constexpr (MASK == 1)       return dpp_mov<0xB1>(v);   // quad_perm [1,0,3,2]
    else if constexpr (MASK == 2)  return dpp_mov<0x4E>(v);   // quad_perm [2,3,0,1]
    else if constexpr (MASK == 4) {
        float lo = dpp_mov<0x114>(v);   // row_shr:4 -> dst[i] = src[i-4] (i%16>=4)
        float hi = dpp_mov<0x104>(v);   // row_shl:4 -> dst[i] = src[i+4] (i%16<12)
        return (lane & 4) ? lo : hi;    // valid exactly where selected
    }
    else if constexpr (MASK == 8)  return dpp_mov<0x128>(v);  // row_ror:8 == xor 8
    else                           return __shfl_xor(v, MASK); // 16/32: ds_swizzle
}

// ---- 32-reg gate helpers ----
template <int B>
__device__ __forceinline__ void pair_bit32(float (&a)[32], float s, float c, int swap) {
#pragma unroll
    for (int g = 0; g < 16; ++g) {
        int r0 = ((g >> B) << (B + 1)) | (g & ((1 << B) - 1));
        int r1 = r0 | (1 << B);
        float v0 = a[r0], v1 = a[r1];
        float o0 = c * v0 - s * v1;
        float o1 = s * v0 + c * v1;
        a[r0] = swap ? o1 : o0;
        a[r1] = swap ? o0 : o1;
    }
}
// Fused RY(tgt = reg bit BT) then CNOT(ctrl = reg bit BT+1, tgt = reg bit BT).
template <int BT>
__device__ __forceinline__ void quad_gate32(float (&a)[32], float s, float c) {
#pragma unroll
    for (int g = 0; g < 8; ++g) {
        int lo  = g & ((1 << BT) - 1);
        int r00 = ((g >> BT) << (BT + 2)) | lo;
        int r01 = r00 | (1 << BT);
        int r10 = r00 | (2 << BT);
        int r11 = r00 | (3 << BT);
        float v00 = a[r00], v01 = a[r01], v10 = a[r10], v11 = a[r11];
        a[r00] = c * v00 - s * v01;
        a[r01] = s * v00 + c * v01;
        a[r10] = s * v10 + c * v11;   // ctrl=1 half: RY then swap (CNOT)
        a[r11] = c * v10 - s * v11;
    }
}
// Fused RY+CNOT lane gate: tgt = lane bit of MASK, ctrl = lane bit of 2*MASK.
template <int MASK>
__device__ __forceinline__ void lane_gate32(float (&a)[32], float s, float c, int lane) {
    const int tau = (lane & MASK) ? 1 : 0;
    const int gam = (lane & (MASK << 1)) ? 1 : 0;
    const float A = gam ? (tau ? -s : s) : c;
    const float B = gam ? c : (tau ? s : -s);
#pragma unroll
    for (int r = 0; r < 32; ++r) {
        float p = xor_lanes<MASK>(a[r], lane);
        a[r] = A * a[r] + B * p;
    }
}
// Lane gate with per-REG ctrl (reg bit 0): tgt = lane bit of MASK.
template <int MASK>
__device__ __forceinline__ void lane_gate32_regctrl(float (&a)[32], float s, float c,
                                                    int lane, int tau) {
    const float A0 = c,            B0 = tau ? s : -s;   // gam = 0 (even regs)
    const float A1 = tau ? -s : s, B1 = c;              // gam = 1 (odd regs)
#pragma unroll
    for (int r = 0; r < 32; ++r) {
        float p = xor_lanes<MASK>(a[r], lane);
        float A = (r & 1) ? A1 : A0;
        float B = (r & 1) ? B1 : B0;
        a[r] = A * a[r] + B * p;
    }
}

// Shared pass1 body: from a[] in L0 layout, apply qubits 0..9 of block `ang`,
// store pi2 to dst. L0: regs r = e19..23, w = e15..18, lane = (e0..4, e14@5).
// T1 (2 rounds by e23 = reg bit4 both sides; identity map, conflict-free):
//   L1: regs k = (e15..18 @0..3, e23@4), lane = (e0..4, e14@5), w = e19..22.
__device__ __forceinline__ void p1_body(float (&a)[32], float* __restrict__ lds,
                                        float* __restrict__ dst, int blk,
                                        const float* __restrict__ scs,
                                        const float* __restrict__ scc,
                                        int lane, int w) {
    pair_bit32<4>(a, scs[0], scc[0], 0);         // q0: tgt e23
    quad_gate32<3>(a, scs[1], scc[1]);           // q1: tgt e22 ctrl e23
    quad_gate32<2>(a, scs[2], scc[2]);
    quad_gate32<1>(a, scs[3], scc[3]);
    quad_gate32<0>(a, scs[4], scc[4]);           // q4: tgt e19 ctrl e20

    // T1: rounds x = e23; 16K floats/round (64 KiB LDS).
#pragma unroll
    for (int x = 0; x < 2; ++x) {
        __syncthreads();
#pragma unroll
        for (int j = 0; j < 16; ++j)
            lds[lane | (w << 6) | (j << 10)] = a[(x << 4) | j];
        __syncthreads();
#pragma unroll
        for (int m = 0; m < 16; ++m)
            a[(x << 4) | m] = lds[lane | (m << 6) | (w << 10)];
    }

    pair_bit32<3>(a, scs[5], scc[5], w & 1);     // q5: tgt e18 ctrl e19
    quad_gate32<2>(a, scs[6], scc[6]);           // q6: tgt e17 ctrl e18
    quad_gate32<1>(a, scs[7], scc[7]);           // q7: tgt e16 ctrl e17
    quad_gate32<0>(a, scs[8], scc[8]);           // q8: tgt e15 ctrl e16

    // q9: RY tgt e14 (lane bit 5) + CNOT ctrl e15 (reg bit 0): shfl mask 32.
    lane_gate32_regctrl<32>(a, scs[9], scc[9], lane, (lane >> 5) & 1);

    // store pi2: G = e14(lane5) | (k&15)<<1 [e15..18] | w<<5 [e19..22] | (k>>4)<<9 [e23]
#pragma unroll
    for (int k = 0; k < 32; ++k) {
        int G = ((lane >> 5) & 1) | ((k & 15) << 1) | (w << 5) | ((k >> 4) << 9);
        dst[((size_t)blk << 15) | (G << 5) | (size_t)(lane & 31)] = a[k];
    }
}

// ---------------- Pass 1 (std -> pi2): qubits 0..9 of block b ------------------
__global__ __launch_bounds__(1024, 2)
void pass1_pi_kernel(const float* __restrict__ src, float* __restrict__ dst,
                     const float* __restrict__ angles, int blk_b) {
    __shared__ float lds[16384];
    __shared__ float scs[10], scc[10];
    const int tid  = threadIdx.x;
    const int lane = tid & 63;
    const int w    = tid >> 6;                   // 0..15 = e15..18
    const int blk  = blockIdx.x;                 // e5..13 (9 bits)
    const float* ang = angles + blk_b * N_QUBITS;

    if (tid < 10) {
        float s, c;
        sincosf(0.5f * ang[tid], &s, &c);
        scs[tid] = s; scc[tid] = c;
    }

    float a[32];
    // read std: addr = r<<19 | w<<15 | (lane5=e14)<<14 | blk<<5 | lane&31
#pragma unroll
    for (int r = 0; r < 32; ++r)
        a[r] = src[((size_t)r << 19) | ((size_t)w << 15) | ((size_t)(lane >> 5) << 14)
                   | ((size_t)blk << 5) | (size_t)(lane & 31)];
    __syncthreads();                             // table ready

    p1_body(a, lds, dst, blk, scs, scc, lane, w);
}

// ---------------- Fused: block0 analytic + block1 qubits 0..9 -> pi2 -----------
// No global reads. f10 (1024 amps, block0 q0..9) via LDS sim; g via per-thread
// 14-factor product; a[r] = f10[(r<<5)|(w<<1)|e14] * g_c[blk<<5 | e0..4].
__global__ __launch_bounds__(1024, 2)
void fused_init_p1_kernel(float* __restrict__ dst, const float* __restrict__ angles) {
    __shared__ float lds[16384];
    __shared__ float s0[24], c0[24];             // block 0
    __shared__ float s1[10], c1[10];             // block 1
    const int tid  = threadIdx.x;
    const int lane = tid & 63;
    const int w    = tid >> 6;
    const int blk  = blockIdx.x;                 // e5..13

    if (tid < 24) {
        float s, c;
        sincosf(0.5f * angles[tid], &s, &c);
        s0[tid] = s; c0[tid] = c;
    } else if (tid >= 32 && tid < 42) {
        float s, c;
        sincosf(0.5f * angles[N_QUBITS + (tid - 32)], &s, &c);
        s1[tid - 32] = s; c1[tid - 32] = c;
    }

    // f10 sim in lds[0..1023]: index bit k = e(14+k); qubit q -> f bit (9-q).
    float* f = lds;
    f[tid] = 0.0f;
    __syncthreads();
    if (tid == 0) f[0] = 1.0f;
    __syncthreads();
    if (tid < 512) {                             // q0: tgt f bit 9 (e23)
        float s = s0[0], c = c0[0];
        float v0 = f[tid], v1 = f[tid | 512];
        f[tid]       = c * v0 - s * v1;
        f[tid | 512] = s * v0 + c * v1;
    }
    __syncthreads();
    for (int q = 1; q <= 9; ++q) {
        int bt = 9 - q;                          // 8..0
        if (tid < 256) {
            float s = s0[q], c = c0[q];
            int lo  = tid & ((1 << bt) - 1);
            int r00 = ((tid >> bt) << (bt + 2)) | lo;
            int r01 = r00 | (1 << bt);
            int r10 = r00 | (2 << bt);
            int r11 = r00 | (3 << bt);
            float v00 = f[r00], v01 = f[r01], v10 = f[r10], v11 = f[r11];
            f[r00] = c * v00 - s * v01;
            f[r01] = s * v00 + c * v01;
            f[r10] = s * v10 + c * v11;
            f[r11] = c * v10 - s * v11;
        }
        __syncthreads();
    }

    // g_c[low14]: low = blk<<5 | (lane&31) (bits e0..13), chain seed c = e14.
    float gval = 1.0f;
    {
        const int low = (blk << 5) | (lane & 31);
        int prev = (lane >> 5) & 1;              // e14
#pragma unroll
        for (int q = 10; q <= 23; ++q) {
            const int bt = 23 - q;               // 13..0
            const int b = (low >> bt) & 1;
            gval *= (b ^ prev) ? s0[q] : c0[q];
            prev = b;
        }
    }

    // synthesize input amps (L0 layout): chunk = (r<<5)|(w<<1)|e14
    float a[32];
#pragma unroll
    for (int r = 0; r < 32; ++r)
        a[r] = f[(r << 5) | (w << 1) | (lane >> 5)] * gval;
    // (p1_body's first __syncthreads orders these f-reads before T1 overwrites lds)

    p1_body(a, lds, dst, blk, s1, c1, lane, w);
}

// ---------------- Pass 2+3 tail: qubits 10..23 on a 16384-float chunk ----------
// L0 (entry): regs r = e9..13, w = e6..8, lane = e0..5. chunk = e14..23 (identity).
// T1 (2 rounds by e13 = reg bit 4 both sides; identity map):
//   L1: regs k = (e5..8 @0..3, e13@4), lane = (e0..4, e9@5), w = e10..12.
// scs/scc indexed by (q - 10).
template <bool SQUARE>
__device__ __forceinline__ void p23_tail(float (&a)[32], float* __restrict__ lds,
                                         float* __restrict__ base,
                                         const float* __restrict__ scs,
                                         const float* __restrict__ scc,
                                         int lane, int w, int c14) {
    // phase 1: qubits 10..14 on L0 regs
    pair_bit32<4>(a, scs[0], scc[0], c14);       // q10: tgt e13, ctrl e14
    quad_gate32<3>(a, scs[1], scc[1]);           // q11: tgt e12 ctrl e13
    quad_gate32<2>(a, scs[2], scc[2]);
    quad_gate32<1>(a, scs[3], scc[3]);
    quad_gate32<0>(a, scs[4], scc[4]);           // q14: tgt e9 ctrl e10

    // T1: rounds x = e13; write identity h = lane | w<<6 | j<<9 (h = e0..12)
#pragma unroll
    for (int x = 0; x < 2; ++x) {
        if (x) __syncthreads();
#pragma unroll
        for (int j = 0; j < 16; ++j)
            lds[lane | (w << 6) | (j << 9)] = a[(x << 4) | j];
        __syncthreads();
#pragma unroll
        for (int m = 0; m < 16; ++m)
            a[(x << 4) | m] = lds[(lane & 31) | ((m & 1) << 5) | (((m >> 1) & 7) << 6)
                                  | ((lane >> 5) << 9) | (w << 10)];
    }

    // phase 2: qubits 15..18 on L1 regs (k0..k3 = e5..e8)
    pair_bit32<3>(a, scs[5], scc[5], (lane >> 5) & 1);  // q15: tgt e8 ctrl e9
    quad_gate32<2>(a, scs[6], scc[6]);                  // q16: tgt e7 ctrl e8
    quad_gate32<1>(a, scs[7], scc[7]);                  // q17: tgt e6 ctrl e7
    quad_gate32<0>(a, scs[8], scc[8]);                  // q18: tgt e5 ctrl e6

    // phase 3: lane gates.
    // q19: tgt e4 (mask 16, ds_swizzle), ctrl e5 = reg bit0
    lane_gate32_regctrl<16>(a, scs[9], scc[9], lane, (lane >> 4) & 1);
    lane_gate32<8>(a, scs[10], scc[10], lane);   // q20 (DPP row_ror:8)
    lane_gate32<4>(a, scs[11], scc[11], lane);   // q21 (DPP shr4/shl4 + select)
    lane_gate32<2>(a, scs[12], scc[12], lane);   // q22 (DPP quad_perm)
    lane_gate32<1>(a, scs[13], scc[13], lane);   // q23 (DPP quad_perm)

    if (SQUARE) {
#pragma unroll
        for (int r = 0; r < 32; ++r) a[r] *= a[r];
    }

    // store STANDARD from L1 (14-bit in-chunk addr):
    // addr = e0..4 | e5..8(k&15)<<5 | e9(lane5)<<9 | e10..12(w)<<10 | e13(k4)<<13
#pragma unroll
    for (int k = 0; k < 32; ++k)
        base[(lane & 31) | ((k & 15) << 5) | (((lane >> 5) & 1) << 9)
             | (w << 10) | (((k >> 4) & 1) << 13)] = a[k];
}

// P23: read pi2 from src, write standard to dst. chunk = e14..23 identity.
template <bool SQUARE>
__global__ __launch_bounds__(512, 4)
void pass23_pi_kernel(const float* __restrict__ src, float* __restrict__ dst,
                      const float* __restrict__ angles, int blk_b) {
    __shared__ float lds[8192];
    __shared__ float scs[14], scc[14];
    const int tid  = threadIdx.x;
    const int lane = tid & 63;
    const int w    = tid >> 6;
    const int chunk = blockIdx.x;                // 10 bits, bit k = e(14+k)
    float* __restrict__ base = dst + ((size_t)chunk << 14);
    const int c14 = chunk & 1;                   // e14
    const float* ang = angles + blk_b * N_QUBITS;

    if (tid < 14) {
        float s, c;
        sincosf(0.5f * ang[10 + tid], &s, &c);
        scs[tid] = s; scc[tid] = c;
    }

    float a[32];
    // read pi2: addr = (blk = r<<4 | w<<1 | e5)<<15 | chunk<<5 | e0..4
#pragma unroll
    for (int r = 0; r < 32; ++r)
        a[r] = src[((size_t)((r << 4) | (w << 1) | (lane >> 5)) << 15)
                   | ((size_t)chunk << 5) | (size_t)(lane & 31)];
    __syncthreads();                             // table ready

    p23_tail<SQUARE>(a, lds, base, scs, scc, lane, w, c14);
}

extern "C" void kernel_launch(void* const* d_in, const int* in_sizes, int n_in,
                              void* d_out, int out_size, void* d_ws, size_t ws_size,
                              hipStream_t stream) {
    const float* angles = (const float*)d_in[0];
    float* out = (float*)d_out;
    float* ws  = (float*)d_ws;

    // block 0 (analytic) + block 1 qubits 0..9 -> ws (pi2); no global reads
    fused_init_p1_kernel<<<512, 1024, 0, stream>>>(ws, angles);
    pass23_pi_kernel<false><<<1024, 512, 0, stream>>>(ws, out, angles, 1);

    pass1_pi_kernel<<<512, 1024, 0, stream>>>(out, ws, angles, 2);
    pass23_pi_kernel<false><<<1024, 512, 0, stream>>>(ws, out, angles, 2);

    pass1_pi_kernel<<<512, 1024, 0, stream>>>(out, ws, angles, 3);
    pass23_pi_kernel<true><<<1024, 512, 0, stream>>>(ws, out, angles, 3);
}